// Round 5
// baseline (8419.460 us; speedup 1.0000x reference)
//
#include <hip/hip_runtime.h>

// drosophRNN v5: v2 skeleton (1024 thr, 16 waves, 2 barriers/step, DPP-only
// reductions) with the AV phase algebraically eliminated:
//   AVC(t) = M*V(t) + 0.9^(t+1)*AVC0,  V(t) = 0.9V(t-1) + 0.1 g(t) HD(t),
//   M = (W_HD_AVp - W_HD_AVm) * U  (U = W_AVp_HD == W_AVm_HD)
// -> phase-1 matvec over [HD | V | relu(D7)] (same 100x300 shape as v2);
//    producers maintain V; real AVp/AVm live in 2 spare waves' registers
//    (output-only, one step lagged). Phase 2 = D7 wave only; matvec waves
//    prefetch next step's HD+V slices there. Barriers wait lgkm only.

#define SSTEPS 5000
#define PI_D 3.14159265358979323846

template<int CTRL, int RM, bool BC>
__device__ __forceinline__ float dpp_mov_f(float x) {
  return __int_as_float(__builtin_amdgcn_update_dpp(0, __float_as_int(x), CTRL, RM, 0xF, BC));
}
__device__ __forceinline__ float scan16(float x) {   // lane15 = sum of its 16-row
  x += dpp_mov_f<0x111,0xF,true>(x);
  x += dpp_mov_f<0x112,0xF,true>(x);
  x += dpp_mov_f<0x114,0xF,true>(x);
  x += dpp_mov_f<0x118,0xF,true>(x);
  return x;
}
__device__ __forceinline__ float wave_sum(float x) { // all-VALU (DPP) + readlane
  x = scan16(x);
  x += dpp_mov_f<0x142,0xA,false>(x);  // row_bcast15
  x += dpp_mov_f<0x143,0xC,false>(x);  // row_bcast31
  return __int_as_float(__builtin_amdgcn_readlane(__float_as_int(x), 63));
}
__device__ __forceinline__ float xor1_dpp(float x) { // quad_perm [1,0,3,2]
  return dpp_mov_f<0xB1,0xF,true>(x);
}
// barrier that waits only LDS (global stores stay in flight)
__device__ __forceinline__ void bar_lgkm() {
  asm volatile("s_waitcnt lgkmcnt(0)" ::: "memory");
  __builtin_amdgcn_s_barrier();
  asm volatile("" ::: "memory");
}

__global__ __launch_bounds__(1024, 4) void drosoph_rnn_kernel(
    const float* __restrict__ xin,      // (64,5000,2)
    const float* __restrict__ r0,       // (1,64,300)
    const float* __restrict__ W_HD_HD,  // (100,100)
    const float* __restrict__ W_HD_AVp, // (100,50)
    const float* __restrict__ W_HD_AVm, // (100,50)
    const float* __restrict__ W_AVp_HD, // (50,100)  == W_AVm_HD
    const float* __restrict__ W_AVm_HD, // (50,100)
    const float* __restrict__ W_D7_HD,  // factorized analytically
    const float* __restrict__ W_D7_D7,  // rank-1 (0.002)
    const float* __restrict__ W_HD_D7,  // (100,100)
    float* __restrict__ out)            // 64*5000*300 + 64*300
{
  const int b    = blockIdx.x;
  const int t    = threadIdx.x;
  const int lane = t & 63;
  const int wid  = t >> 6;

  // state per parity: [0..99] HD, [100..199] V, [200..299] relu(D7), [300..327] 0
  __shared__ __align__(16) float su[2][328];
  __shared__ float avb[SSTEPS];
  __shared__ float d7r[104];           // raw D7 of current step

  // ---- roles ----
  const bool p1  = (t < 800);          // matvec: 50 groups x 16 lanes, outputs (g, g+50)
  const int  g   = t >> 4;
  const int  r1  = t & 15;
  const bool d7w = (wid == 13);        // D7 + T0 + HD/D7 output streaming
  const bool avw = (t >= 896);         // waves 14,15: AVp/AVm outputs (register state)
  const int  l2  = t - 896;            // 0..127
  const int  aa  = l2 >> 1;            // AV output index (active < 50)
  const int  ah  = l2 & 1;             // 0: AVp-half j<52, 1: AVm-half j>=48

  const float kAV = 0.70710678118654752f;

  // ---- phase-1 weights: HD cols (10.5*W_HD_HD), V cols (kAV*M), D7 cols (0.5*W_HD_D7)
  float w1[2][20];
  if (p1) {
    #pragma unroll
    for (int k = 0; k < 2; ++k) {
      const int o = g + 50*k;
      #pragma unroll
      for (int q = 0; q < 20; ++q) {
        const int j = 20*r1 + q;
        float w = 0.0f;
        if (j < 100) {
          w = 10.5f * W_HD_HD[o*100 + j];
        } else if (j < 200) {
          const int jj = j - 100;           // M[o][jj] = sum_a (Wp-Wm)[o,a]*U[a,jj]
          float m = 0.f;
          for (int a = 0; a < 50; ++a)
            m = fmaf(W_HD_AVp[o*50+a] - W_HD_AVm[o*50+a], W_AVp_HD[a*100+jj], m);
          w = kAV * m;
        } else if (j < 300) {
          w = 0.5f * W_HD_D7[o*100 + (j-200)];
        }
        w1[k][q] = w;
      }
    }
  }

  // ---- producer extras: AVC0 (initial AV contribution), decay 0.9^s ----
  float avc00 = 0.f, avc01 = 0.f, cdec = 1.0f;
  if (p1 && r1 == 15) {
    const float* r0b = r0 + b*300;
    for (int a = 0; a < 50; ++a) {
      float rp = r0b[100+a], rm = r0b[150+a];
      avc00 = fmaf(W_HD_AVp[g*50+a],      rp, fmaf(W_HD_AVm[g*50+a],      rm, avc00));
      avc01 = fmaf(W_HD_AVp[(g+50)*50+a], rp, fmaf(W_HD_AVm[(g+50)*50+a], rm, avc01));
    }
  }

  // ---- AV output waves: weights + register state ----
  float wav2[52];
  float avst = 0.f;
  if (avw) {
    const int sa = (aa < 50) ? aa : 49;
    #pragma unroll
    for (int q = 0; q < 52; ++q) {
      const int j = 48*ah + q;
      const bool valid = (aa < 50) && (j < 100) && (ah == 0 ? (q < 50) : (q >= 2));
      wav2[q] = valid ? W_AVp_HD[sa*100 + j] : 0.f;
    }
    if (aa < 50) avst = r0[b*300 + 100 + 50*ah + aa];
  }

  // ---- D7 trig constants ----
  float cw0=0.f, cw1=0.f, m0w=0.f, m1w=0.f, sw0=0.f, sw1=0.f;
  float cdA=0.f, sdA=0.f, cdB=0.f, sdB=0.f;
  if (d7w) {
    const int j0 = 2*lane, j1 = 2*lane + 1;
    m0w = (j0 < 100) ? 1.0f : 0.0f;
    m1w = (j1 < 100) ? 1.0f : 0.0f;
    double pj0 = -PI_D + j0*(2.0*PI_D/100.0);
    double pj1 = -PI_D + j1*(2.0*PI_D/100.0);
    cw0 = m0w*(float)cos(pj0);  sw0 = m0w*(float)sin(pj0);
    cw1 = m1w*(float)cos(pj1);  sw1 = m1w*(float)sin(pj1);
    double pa = -PI_D + lane      *(2.0*PI_D/100.0);
    double pb = -PI_D + (lane+64) *(2.0*PI_D/100.0);
    cdA = (float)cos(pa); sdA = (float)sin(pa);
    cdB = (float)cos(pb); sdB = (float)sin(pb);
  }

  // ---- init LDS ----
  if (t < 328) { su[0][t] = 0.f; su[1][t] = 0.f; }   // V(-1)=0 lives here
  if (t < 104) d7r[t] = 0.f;
  {
    const float2* x2 = (const float2*)xin + (size_t)b * SSTEPS;
    for (int i = t; i < SSTEPS; i += 1024) avb[i] = x2[i].y;
  }
  if (t < 100)              su[0][t] = r0[b*300 + t];              // HD init
  if (t >= 200 && t < 300)  su[0][t] = fmaxf(r0[b*300 + t], 0.f);  // relu(D7 init)
  __syncthreads();

  // ---- initial prefetch (state -1 in su[0]) ----
  float4 pre0, pre1, pre2, pre3, pre4;
  float hd0p = 0.f, hd1p = 0.f, v0p = 0.f, v1p = 0.f;
  if (p1) {
    hd0p = su[0][g]; hd1p = su[0][g+50];
    if (r1 < 10) {
      const float4* vp = (const float4*)(su[0] + 20*r1);
      pre0 = vp[0]; pre1 = vp[1]; pre2 = vp[2]; pre3 = vp[3]; pre4 = vp[4];
    }
    if (r1 == 15) { v0p = su[0][100+g]; v1p = su[0][150+g]; }
  }

  float* outb = out + (size_t)b * ((size_t)SSTEPS * 300);
  int p = 0;

  #pragma unroll 1
  for (int s = 0; s < SSTEPS; ++s) {
    const float* suc = su[p];
    float*       sun = su[p^1];
    float T0loc = 0.f;

    // =============== window 1: HD matvec / T0+stream / AV outputs ===============
    if (p1) {
      float vv[20];
      if (r1 >= 10) {     // relu(D7) slices (+pad) - written last phase 2
        const float4* vp = (const float4*)(suc + 20*r1);
        float4 V0=vp[0], V1=vp[1], V2=vp[2], V3=vp[3], V4=vp[4];
        *(float4*)&vv[0]=V0; *(float4*)&vv[4]=V1; *(float4*)&vv[8]=V2;
        *(float4*)&vv[12]=V3; *(float4*)&vv[16]=V4;
      } else {            // HD+V slices: prefetched in last window 2
        *(float4*)&vv[0]=pre0; *(float4*)&vv[4]=pre1; *(float4*)&vv[8]=pre2;
        *(float4*)&vv[12]=pre3; *(float4*)&vv[16]=pre4;
      }
      const float hd0 = hd0p, hd1 = hd1p;
      float xa0=0,xb0=0,xc0=0,xd0=0, xa1=0,xb1=0,xc1=0,xd1=0;
      #define ACC4(BASE, I0,I1,I2,I3) \
        xa0 = fmaf(w1[0][I0], vv[I0], xa0); xb0 = fmaf(w1[0][I1], vv[I1], xb0); \
        xc0 = fmaf(w1[0][I2], vv[I2], xc0); xd0 = fmaf(w1[0][I3], vv[I3], xd0); \
        xa1 = fmaf(w1[1][I0], vv[I0], xa1); xb1 = fmaf(w1[1][I1], vv[I1], xb1); \
        xc1 = fmaf(w1[1][I2], vv[I2], xc1); xd1 = fmaf(w1[1][I3], vv[I3], xd1);
      ACC4(0, 0,1,2,3) ACC4(4, 4,5,6,7) ACC4(8, 8,9,10,11)
      ACC4(12, 12,13,14,15) ACC4(16, 16,17,18,19)
      #undef ACC4
      float e0 = (xa0+xb0)+(xc0+xd0);
      float e1 = (xa1+xb1)+(xc1+xd1);
      if (r1 >= 10) { e0 *= hd0; e1 *= hd1; }   // D7 terms multiply r_HD
      e0 = scan16(e0);
      e1 = scan16(e1);
      if (r1 == 15) {
        const float kc  = cdec * kAV;
        const float e0p = fmaf(kc, avc00, e0);
        const float e1p = fmaf(kc, avc01, e1);
        const float h0  = fmaf(0.001f, fmaf(-10.25f, hd0, e0p), hd0);
        const float h1  = fmaf(0.001f, fmaf(-10.25f, hd1, e1p), hd1);
        sun[g]    = h0;
        sun[g+50] = h1;
        const float gv = avb[s] * 100.0f;       // 0.1 * g(s)
        sun[100+g] = fmaf(gv, h0, 0.9f * v0p);  // V(s)
        sun[150+g] = fmaf(gv, h1, 0.9f * v1p);
      }
      cdec *= 0.9f;
    } else if (d7w) {
      // T0 = sum relu(D7(s-1)) (step-old data)
      float x = 0.f;
      if (lane < 50) { float2 z = *(const float2*)(suc + 200 + 2*lane); x = z.x + z.y; }
      T0loc = wave_sum(x);
      if (s > 0) {   // stream HD + D7 of output row s-1
        float* od = outb + (size_t)(s-1) * 300;
        od[lane]       = suc[lane];
        od[200+lane]   = d7r[lane];
        if (lane < 36) {
          od[64+lane]  = suc[64+lane];
          od[264+lane] = d7r[64+lane];
        }
      }
    } else if (avw) {
      if (s > 0) {   // AVp/AVm(s-1) from HD(s-1)=suc[0..99]; register state
        const float4* hp = (const float4*)(suc + 48*ah);
        float da=0,db=0,dc=0,dd=0;
        #pragma unroll
        for (int kk = 0; kk < 13; ++kk) {
          float4 hh = hp[kk];
          da = fmaf(wav2[4*kk+0], hh.x, da);
          db = fmaf(wav2[4*kk+1], hh.y, db);
          dc = fmaf(wav2[4*kk+2], hh.z, dc);
          dd = fmaf(wav2[4*kk+3], hh.w, dd);
        }
        float d = (da+db)+(dc+dd);
        d += xor1_dpp(d);                         // pair-combine: full dot
        const float gp = avb[s-1] / 0.001f;
        const float gg = ah ? -gp : gp;
        avst = fmaf(0.1f, fmaf(gg, d, -avst), avst);
        if (aa < 50) outb[(size_t)(s-1)*300 + 100 + 50*ah + aa] = avst;
      }
    }
    bar_lgkm();

    // =============== window 2: D7 / prefetch ===============
    if (d7w) {
      float2 y2 = *(const float2*)(sun + 2*lane);   // hdnew (lane>=50 masked x0)
      float y0 = fmaxf(y2.x, 0.f), y1 = fmaxf(y2.y, 0.f);
      float pS0 = fmaf(m1w, y1, m0w * y0);
      float pC  = fmaf(cw1, y1, cw0 * y0);
      float pS  = fmaf(sw1, y1, sw0 * y0);
      float S0 = wave_sum(pS0);
      float C  = wave_sum(pC);
      float S  = wave_sum(pS);
      float base = fmaf(0.002f, T0loc, 0.01f * S0);
      {
        float d7 = base - 0.01f * fmaf(cdA, C, sdA * S);
        sun[200+lane] = fmaxf(d7, 0.f);
        d7r[lane]     = d7;
      }
      if (lane < 36) {
        float d7 = base - 0.01f * fmaf(cdB, C, sdB * S);
        sun[264+lane] = fmaxf(d7, 0.f);
        d7r[64+lane]  = d7;
      }
    } else if (p1) {
      // prefetch next step's HD+V slices (written in window 1, stable now)
      hd0p = sun[g]; hd1p = sun[g+50];
      if (r1 < 10) {
        const float4* vp = (const float4*)(sun + 20*r1);
        pre0 = vp[0]; pre1 = vp[1]; pre2 = vp[2]; pre3 = vp[3]; pre4 = vp[4];
      }
      if (r1 == 15) { v0p = sun[100+g]; v1p = sun[150+g]; }
    }
    bar_lgkm();
    p ^= 1;
  }

  // =============== epilogue: row 4999 + final carry ===============
  {
    float* od    = outb + (size_t)(SSTEPS-1) * 300;
    float* carry = out + (size_t)64 * SSTEPS * 300 + (size_t)b * 300;
    if (t < 100) { od[t] = su[p][t]; carry[t] = su[p][t]; }
    if (t >= 200 && t < 300) { int i = t - 200; od[t] = d7r[i]; carry[t] = d7r[i]; }
    if (avw) {   // final AV update with g(4999), HD(4999)
      const float4* hp = (const float4*)(su[p] + 48*ah);
      float da=0,db=0,dc=0,dd=0;
      #pragma unroll
      for (int kk = 0; kk < 13; ++kk) {
        float4 hh = hp[kk];
        da = fmaf(wav2[4*kk+0], hh.x, da);
        db = fmaf(wav2[4*kk+1], hh.y, db);
        dc = fmaf(wav2[4*kk+2], hh.z, dc);
        dd = fmaf(wav2[4*kk+3], hh.w, dd);
      }
      float d = (da+db)+(dc+dd);
      d += xor1_dpp(d);
      const float gp = avb[SSTEPS-1] / 0.001f;
      const float gg = ah ? -gp : gp;
      avst = fmaf(0.1f, fmaf(gg, d, -avst), avst);
      if (aa < 50) {
        od[100 + 50*ah + aa]    = avst;
        carry[100 + 50*ah + aa] = avst;
      }
    }
  }
}

extern "C" void kernel_launch(void* const* d_in, const int* in_sizes, int n_in,
                              void* d_out, int out_size, void* d_ws, size_t ws_size,
                              hipStream_t stream) {
  drosoph_rnn_kernel<<<64, 1024, 0, stream>>>(
      (const float*)d_in[0],  // inputs
      (const float*)d_in[1],  // r0
      (const float*)d_in[2],  // W_HD_HD
      (const float*)d_in[3],  // W_HD_AVplus
      (const float*)d_in[4],  // W_HD_AVminus
      (const float*)d_in[5],  // W_AVplus_HD
      (const float*)d_in[6],  // W_AVminus_HD
      (const float*)d_in[7],  // W_Del7_HD
      (const float*)d_in[8],  // W_Del7_Del7
      (const float*)d_in[9],  // W_HD_Del7
      (float*)d_out);
}

// Round 6
// 4360.391 us; speedup vs baseline: 1.9309x; 1.9309x over previous
//
#include <hip/hip_runtime.h>

// drosophRNN v6: v2 skeleton (16 waves, 2 barriers/step, DPP-only reductions,
// NO prefetch) with three fixes:
//  1) amdgpu_waves_per_eu(4,4): VGPR cap 128, stops the 64-VGPR spill squeeze (v5 lesson)
//  2) lgkm-only barriers: global stores don't drain at s_barrier (v2's hidden cost)
//  3) AV phase eliminated algebraically (v5 math, validated):
//       AVC(t) = M*V(t) + 0.9^(t+1)*AVC0,  V(t) = 0.9 V(t-1) + 0.1 g(t) HD(t)
//     matvec over [HD | V | reluD7]; real AVp/AVm = output-only register state.

#define SSTEPS 5000
#define PI_D 3.14159265358979323846

template<int CTRL, int RM, bool BC>
__device__ __forceinline__ float dpp_mov_f(float x) {
  return __int_as_float(__builtin_amdgcn_update_dpp(0, __float_as_int(x), CTRL, RM, 0xF, BC));
}
__device__ __forceinline__ float scan16(float x) {   // lane15 = sum of its 16-row
  x += dpp_mov_f<0x111,0xF,true>(x);
  x += dpp_mov_f<0x112,0xF,true>(x);
  x += dpp_mov_f<0x114,0xF,true>(x);
  x += dpp_mov_f<0x118,0xF,true>(x);
  return x;
}
__device__ __forceinline__ float scan8(float x) {    // lane7 = sum of its 8-group
  x += dpp_mov_f<0x111,0xF,true>(x);
  x += dpp_mov_f<0x112,0xF,true>(x);
  x += dpp_mov_f<0x114,0xF,true>(x);
  return x;
}
__device__ __forceinline__ float wave_sum(float x) { // all-VALU (DPP) + readlane
  x = scan16(x);
  x += dpp_mov_f<0x142,0xA,false>(x);  // row_bcast15
  x += dpp_mov_f<0x143,0xC,false>(x);  // row_bcast31
  return __int_as_float(__builtin_amdgcn_readlane(__float_as_int(x), 63));
}
// barrier that waits only LDS (global stores stay in flight)
__device__ __forceinline__ void bar_lgkm() {
  __builtin_amdgcn_sched_barrier(0);
  asm volatile("s_waitcnt lgkmcnt(0)" ::: "memory");
  __builtin_amdgcn_s_barrier();
  __builtin_amdgcn_sched_barrier(0);
}

__global__
__attribute__((amdgpu_flat_work_group_size(1024,1024)))
__attribute__((amdgpu_waves_per_eu(4,4)))
void drosoph_rnn_kernel(
    const float* __restrict__ xin,      // (64,5000,2)
    const float* __restrict__ r0,       // (1,64,300)
    const float* __restrict__ W_HD_HD,  // (100,100)
    const float* __restrict__ W_HD_AVp, // (100,50)
    const float* __restrict__ W_HD_AVm, // (100,50)
    const float* __restrict__ W_AVp_HD, // (50,100) == W_AVm_HD
    const float* __restrict__ W_AVm_HD, // (50,100)
    const float* __restrict__ W_D7_HD,  // factorized analytically
    const float* __restrict__ W_D7_D7,  // rank-1 (0.002)
    const float* __restrict__ W_HD_D7,  // (100,100)
    float* __restrict__ out)            // 64*5000*300 + 64*300
{
  const int b    = blockIdx.x;
  const int t    = threadIdx.x;
  const int lane = t & 63;
  const int wid  = t >> 6;

  // state per parity: [0..99] HD, [100..199] V, [200..299] relu(D7), [300..327] 0
  __shared__ __align__(16) float su[2][328];
  __shared__ float avb[SSTEPS];
  __shared__ float d7r[104];           // raw D7 of current step

  // ---- roles ----
  const bool p1  = (t < 800);          // matvec: 50 groups x 16 lanes -> outputs (g, g+50)
  const int  g   = t >> 4;
  const int  r1  = t & 15;
  const bool pav = (t < 400);          // window2: AV outputs, 50 groups x 8 lanes
  const int  a   = t >> 3;
  const int  qa  = t & 7;
  const bool d7w = (wid == 13) || (wid == 14);
  const int  o7  = (wid - 13) * 64 + lane;   // D7 output (valid < 100)
  const bool pst = (wid == 15);        // output streaming wave

  const float kAV = 0.70710678118654752f;

  // ---- matvec weights: HD cols 10.5*W_HD_HD, V cols kAV*M, D7 cols 0.5*W_HD_D7 ----
  float w1[2][20];
  if (p1) {
    #pragma unroll
    for (int k = 0; k < 2; ++k) {
      const int o = g + 50*k;
      #pragma unroll
      for (int q = 0; q < 20; ++q) {
        const int j = 20*r1 + q;
        float w = 0.0f;
        if (j < 100) {
          w = 10.5f * W_HD_HD[o*100 + j];
        } else if (j < 200) {
          const int jj = j - 100;       // M[o][jj] = sum_a (Wp-Wm)[o,a]*U[a,jj]
          float m = 0.f;
          for (int aa = 0; aa < 50; ++aa)
            m = fmaf(W_HD_AVp[o*50+aa] - W_HD_AVm[o*50+aa], W_AVp_HD[aa*100+jj], m);
          w = kAV * m;
        } else if (j < 300) {
          w = 0.5f * W_HD_D7[o*100 + (j-200)];
        }
        w1[k][q] = w;
      }
    }
  }

  // ---- producer extras: AVC0 + decay ----
  float avc00 = 0.f, avc01 = 0.f, cdec = 1.0f;
  if (p1 && r1 == 15) {
    const float* r0b = r0 + b*300;
    for (int aa = 0; aa < 50; ++aa) {
      float rp = r0b[100+aa], rm = r0b[150+aa];
      avc00 = fmaf(W_HD_AVp[g*50+aa],      rp, fmaf(W_HD_AVm[g*50+aa],      rm, avc00));
      avc01 = fmaf(W_HD_AVp[(g+50)*50+aa], rp, fmaf(W_HD_AVm[(g+50)*50+aa], rm, avc01));
    }
  }

  // ---- AV output weights (v2 layout: chunks qa, qa+8, qa+16, qa+24) + reg state ----
  float wav[16];
  float avstP = 0.f, avstM = 0.f;
  if (pav) {
    #pragma unroll
    for (int u = 0; u < 4; ++u) {
      const int j0 = 4*(qa + 8*u);
      #pragma unroll
      for (int m = 0; m < 4; ++m) {
        const int j = j0 + m;
        wav[4*u+m] = (j < 100) ? W_AVp_HD[a*100 + j] : 0.0f;
      }
    }
    if (qa == 7) {
      avstP = r0[b*300 + 100 + a];
      avstM = r0[b*300 + 150 + a];
    }
  }

  // ---- D7 trig constants ----
  float cw0=0.f, cw1=0.f, m0w=0.f, m1w=0.f, sw0=0.f, sw1=0.f, cd=0.f, sd=0.f;
  if (d7w) {
    const int j0 = 2*lane, j1 = 2*lane + 1;
    m0w = (j0 < 100) ? 1.0f : 0.0f;
    m1w = (j1 < 100) ? 1.0f : 0.0f;
    double pj0 = -PI_D + j0*(2.0*PI_D/100.0);
    double pj1 = -PI_D + j1*(2.0*PI_D/100.0);
    cw0 = m0w*(float)cos(pj0);  sw0 = m0w*(float)sin(pj0);
    cw1 = m1w*(float)cos(pj1);  sw1 = m1w*(float)sin(pj1);
    double po = -PI_D + o7*(2.0*PI_D/100.0);
    cd = (float)cos(po); sd = (float)sin(po);
  }

  // ---- init LDS ----
  if (t < 328) { su[0][t] = 0.f; su[1][t] = 0.f; }   // V(-1) = 0
  if (t < 104) d7r[t] = 0.f;
  {
    const float2* x2 = (const float2*)xin + (size_t)b * SSTEPS;
    for (int i = t; i < SSTEPS; i += 1024) avb[i] = x2[i].y;
  }
  if (t < 100)              su[0][t] = r0[b*300 + t];              // HD init
  if (t >= 200 && t < 300)  su[0][t] = fmaxf(r0[b*300 + t], 0.f);  // relu(D7) init
  __syncthreads();

  float* outb = out + (size_t)b * ((size_t)SSTEPS * 300);
  int p = 0;

  #pragma unroll 1
  for (int s = 0; s < SSTEPS; ++s) {
    const float* suc = su[p];
    float*       sun = su[p^1];
    float T0loc = 0.f;

    // =============== window 1: HD matvec / T0 / stream ===============
    if (p1) {
      float vv[20];
      {
        const float4* vp = (const float4*)(suc + 20*r1);
        float4 V0=vp[0], V1=vp[1], V2=vp[2], V3=vp[3], V4=vp[4];
        *(float4*)&vv[0]=V0; *(float4*)&vv[4]=V1; *(float4*)&vv[8]=V2;
        *(float4*)&vv[12]=V3; *(float4*)&vv[16]=V4;
      }
      const float hd0 = suc[g];
      const float hd1 = suc[g+50];
      float xa0=0,xb0=0,xc0=0,xd0=0, xa1=0,xb1=0,xc1=0,xd1=0;
      #define ACC4(I0,I1,I2,I3) \
        xa0 = fmaf(w1[0][I0], vv[I0], xa0); xb0 = fmaf(w1[0][I1], vv[I1], xb0); \
        xc0 = fmaf(w1[0][I2], vv[I2], xc0); xd0 = fmaf(w1[0][I3], vv[I3], xd0); \
        xa1 = fmaf(w1[1][I0], vv[I0], xa1); xb1 = fmaf(w1[1][I1], vv[I1], xb1); \
        xc1 = fmaf(w1[1][I2], vv[I2], xc1); xd1 = fmaf(w1[1][I3], vv[I3], xd1);
      ACC4(0,1,2,3) ACC4(4,5,6,7) ACC4(8,9,10,11) ACC4(12,13,14,15) ACC4(16,17,18,19)
      #undef ACC4
      float e0 = (xa0+xb0)+(xc0+xd0);
      float e1 = (xa1+xb1)+(xc1+xd1);
      if (r1 >= 10) { e0 *= hd0; e1 *= hd1; }   // D7 cols multiply r_HD
      e0 = scan16(e0);
      e1 = scan16(e1);
      if (r1 == 15) {
        const float v0p = suc[100+g];
        const float v1p = suc[150+g];
        const float kc  = cdec * kAV;
        const float e0p = fmaf(kc, avc00, e0);
        const float e1p = fmaf(kc, avc01, e1);
        const float h0  = fmaf(0.001f, fmaf(-10.25f, hd0, e0p), hd0);
        const float h1  = fmaf(0.001f, fmaf(-10.25f, hd1, e1p), hd1);
        sun[g]    = h0;
        sun[g+50] = h1;
        const float gv = avb[s] * 100.0f;        // 0.1 * g(s)
        sun[100+g] = fmaf(gv, h0, 0.9f * v0p);   // V(s)
        sun[150+g] = fmaf(gv, h1, 0.9f * v1p);
      }
      cdec *= 0.9f;
    } else if (d7w) {
      // T0 = sum relu(D7(s-1)) — step-old data
      float x = 0.f;
      if (lane < 50) { float2 z = *(const float2*)(suc + 200 + 2*lane); x = z.x + z.y; }
      T0loc = wave_sum(x);
    } else if (pst) {
      if (s > 0) {   // stream HD + D7 of row s-1 (AV cols written by pav lanes)
        float* od = outb + (size_t)(s-1) * 300;
        od[lane]       = suc[lane];
        od[200+lane]   = d7r[lane];
        if (lane < 36) {
          od[64+lane]  = suc[64+lane];
          od[264+lane] = d7r[64+lane];
        }
      }
    }
    bar_lgkm();

    // =============== window 2: AV outputs / D7 ===============
    if (pav) {
      const float4* hp = (const float4*)sun;    // hdnew[0..99]; j>=100 lanes x 0-weights
      float4 H0 = hp[qa], H1 = hp[qa+8], H2 = hp[qa+16], H3 = hp[qa+24];
      float da=0,db=0,dc=0,dd=0;
      da = fmaf(wav[0],  H0.x, da); db = fmaf(wav[1],  H0.y, db);
      dc = fmaf(wav[2],  H0.z, dc); dd = fmaf(wav[3],  H0.w, dd);
      da = fmaf(wav[4],  H1.x, da); db = fmaf(wav[5],  H1.y, db);
      dc = fmaf(wav[6],  H1.z, dc); dd = fmaf(wav[7],  H1.w, dd);
      da = fmaf(wav[8],  H2.x, da); db = fmaf(wav[9],  H2.y, db);
      dc = fmaf(wav[10], H2.z, dc); dd = fmaf(wav[11], H2.w, dd);
      da = fmaf(wav[12], H3.x, da); db = fmaf(wav[13], H3.y, db);
      dc = fmaf(wav[14], H3.z, dc); dd = fmaf(wav[15], H3.w, dd);
      float d = scan8((da+db)+(dc+dd));
      if (qa == 7) {
        const float gp = avb[s] * 1000.0f;       // av/DT
        avstP = fmaf(0.1f, fmaf(gp,  d, -avstP), avstP);   // DT/TAU_AV = 0.1
        avstM = fmaf(0.1f, fmaf(-gp, d, -avstM), avstM);
        float* od = outb + (size_t)s * 300;
        od[100+a] = avstP;
        od[150+a] = avstM;
      }
    }
    if (d7w) {
      float2 y2 = *(const float2*)(sun + 2*lane);   // hdnew (lane>=50 masked x0)
      float y0 = fmaxf(y2.x, 0.f), y1 = fmaxf(y2.y, 0.f);
      float pS0 = fmaf(m1w, y1, m0w * y0);
      float pC  = fmaf(cw1, y1, cw0 * y0);
      float pS  = fmaf(sw1, y1, sw0 * y0);
      float S0 = wave_sum(pS0);
      float C  = wave_sum(pC);
      float S  = wave_sum(pS);
      if (o7 < 100) {
        float d7 = fmaf(0.002f, T0loc, 0.01f * (S0 - fmaf(cd, C, sd * S)));
        sun[200+o7] = fmaxf(d7, 0.f);
        d7r[o7]     = d7;
      }
    }
    bar_lgkm();
    p ^= 1;
  }

  // =============== epilogue: row 4999 HD/D7 + final carry ===============
  {
    float* od    = outb + (size_t)(SSTEPS-1) * 300;
    float* carry = out + (size_t)64 * SSTEPS * 300 + (size_t)b * 300;
    if (t < 100)             { od[t] = su[p][t];    carry[t] = su[p][t]; }
    if (t >= 200 && t < 300) { int i = t-200; od[t] = d7r[i]; carry[t] = d7r[i]; }
    if (pav && qa == 7) {
      carry[100+a] = avstP;
      carry[150+a] = avstM;
    }
  }
}

extern "C" void kernel_launch(void* const* d_in, const int* in_sizes, int n_in,
                              void* d_out, int out_size, void* d_ws, size_t ws_size,
                              hipStream_t stream) {
  drosoph_rnn_kernel<<<64, 1024, 0, stream>>>(
      (const float*)d_in[0],  // inputs
      (const float*)d_in[1],  // r0
      (const float*)d_in[2],  // W_HD_HD
      (const float*)d_in[3],  // W_HD_AVplus
      (const float*)d_in[4],  // W_HD_AVminus
      (const float*)d_in[5],  // W_AVplus_HD
      (const float*)d_in[6],  // W_AVminus_HD
      (const float*)d_in[7],  // W_Del7_HD
      (const float*)d_in[8],  // W_Del7_Del7
      (const float*)d_in[9],  // W_HD_Del7
      (float*)d_out);
}

// Round 7
// 3913.018 us; speedup vs baseline: 2.1517x; 1.1143x over previous
//
#include <hip/hip_runtime.h>

// drosophRNN v7: exactly the v2 structure (fastest so far, 3979us) with ONE
// change: dot-product FMAs packed into v_pk_fma_f32 (2 fp32 FMA per inst).
// Phase1: 40 scalar FMA -> 20 pk_fma per lane. AV: 16 -> 8.
// Rationale: per-active-CU VALUBusy ~65% => VALU-issue-bound; packing halves
// the dominant instruction stream. All else (roles, barriers, LDS layout,
// D7 factorization, streaming wave) identical to v2.

#define SSTEPS 5000
#define PI_D 3.14159265358979323846

typedef float f2 __attribute__((ext_vector_type(2)));

__device__ __forceinline__ f2 pk_fma(f2 a, f2 b, f2 c) {
  f2 d;
  asm("v_pk_fma_f32 %0, %1, %2, %3" : "=v"(d) : "v"(a), "v"(b), "v"(c));
  return d;
}

template<int CTRL, int RM, bool BC>
__device__ __forceinline__ float dpp_mov_f(float x) {
  return __int_as_float(__builtin_amdgcn_update_dpp(0, __float_as_int(x), CTRL, RM, 0xF, BC));
}
__device__ __forceinline__ float scan16(float x) {   // lane15 = sum of its 16-row
  x += dpp_mov_f<0x111,0xF,true>(x);
  x += dpp_mov_f<0x112,0xF,true>(x);
  x += dpp_mov_f<0x114,0xF,true>(x);
  x += dpp_mov_f<0x118,0xF,true>(x);
  return x;
}
__device__ __forceinline__ float scan8(float x) {    // lane7 = sum of its 8-group
  x += dpp_mov_f<0x111,0xF,true>(x);
  x += dpp_mov_f<0x112,0xF,true>(x);
  x += dpp_mov_f<0x114,0xF,true>(x);
  return x;
}
__device__ __forceinline__ float wave_sum(float x) { // all-VALU (DPP) + readlane
  x = scan16(x);
  x += dpp_mov_f<0x142,0xA,false>(x);  // row_bcast15
  x += dpp_mov_f<0x143,0xC,false>(x);  // row_bcast31
  return __int_as_float(__builtin_amdgcn_readlane(__float_as_int(x), 63));
}

__global__ __launch_bounds__(1024, 4) void drosoph_rnn_kernel(
    const float* __restrict__ xin,      // (64,5000,2)
    const float* __restrict__ r0,       // (1,64,300)
    const float* __restrict__ W_HD_HD,  // (100,100)
    const float* __restrict__ W_HD_AVp, // (100,50)
    const float* __restrict__ W_HD_AVm, // (100,50)
    const float* __restrict__ W_AVp_HD, // (50,100)
    const float* __restrict__ W_AVm_HD, // (50,100)  (== W_AVp_HD)
    const float* __restrict__ W_D7_HD,  // factorized analytically
    const float* __restrict__ W_D7_D7,  // rank-1 (0.002)
    const float* __restrict__ W_HD_D7,  // (100,100)
    float* __restrict__ out)            // 64*5000*300 + 64*300
{
  const int b    = blockIdx.x;
  const int t    = threadIdx.x;
  const int lane = t & 63;
  const int wid  = t >> 6;

  // state per parity: [0..99] HD, [100..149] AVp, [150..199] AVm,
  // [200..299] relu(D7), [300..327] zero pad
  __shared__ __align__(16) float su[2][328];
  __shared__ float avb[SSTEPS];   // x[:,1] for this batch
  __shared__ float d7r[104];      // raw D7 (current step)

  // ---- roles (identical to v2) ----
  const bool p1  = (t < 800);            // phase1: 50 pairs x 16 lanes
  const int  g   = t >> 4;               // pair -> outputs (g, g+50)
  const int  r1  = t & 15;               // j-slice [20*r1, 20*r1+20)
  const bool pav = (t < 400);            // AV: 50 groups x 8 lanes (one shared dot)
  const int  a   = t >> 3;
  const int  qa  = t & 7;
  const bool pd7 = (t >= 832) && (t < 960); // two full waves
  const int  dl  = t & 63;
  const int  o7  = t - 832;              // D7 output (valid if pd7 && o7<100)
  const bool pst = (t >= 960);           // wave 15: output streaming

  // ---- phase-1 weights (scales folded), packed into float2 pairs ----
  f2 w1p[2][10];
  if (p1) {
    #pragma unroll
    for (int k = 0; k < 2; ++k) {
      const int o = g + 50*k;
      #pragma unroll
      for (int q = 0; q < 20; ++q) {
        const int j = 20*r1 + q;
        float w;
        if      (j < 100) w = 10.5f                * W_HD_HD [o*100 + j];
        else if (j < 150) w = 0.70710678118654752f * W_HD_AVp[o*50 + (j-100)];
        else if (j < 200) w = 0.70710678118654752f * W_HD_AVm[o*50 + (j-150)];
        else if (j < 300) w = 0.5f                 * W_HD_D7 [o*100 + (j-200)];
        else w = 0.0f;
        w1p[k][q >> 1][q & 1] = w;
      }
    }
  }

  // ---- AV weights, chunk-interleaved (qa, qa+8, qa+16, qa+24), packed ----
  f2 wavp[8];
  if (pav) {
    #pragma unroll
    for (int u = 0; u < 4; ++u) {
      const int j0 = 4*(qa + 8*u);
      #pragma unroll
      for (int m = 0; m < 4; ++m) {
        const int j = j0 + m;
        float w = (j < 100) ? W_AVp_HD[a*100 + j] : 0.0f;
        wavp[2*u + (m >> 1)][m & 1] = w;
      }
    }
  }

  // ---- D7 factorization constants ----
  float cw0=0.f, cw1=0.f, sw0=0.f, sw1=0.f, m0w=0.f, m1w=0.f, cd=0.f, sd=0.f;
  if (pd7) {
    const int j0 = 2*dl, j1 = 2*dl + 1;
    double pj0 = -PI_D + j0*(2.0*PI_D/100.0);
    double pj1 = -PI_D + j1*(2.0*PI_D/100.0);
    m0w = (j0 < 100) ? 1.0f : 0.0f;
    m1w = (j1 < 100) ? 1.0f : 0.0f;
    cw0 = m0w * (float)cos(pj0);  sw0 = m0w * (float)sin(pj0);
    cw1 = m1w * (float)cos(pj1);  sw1 = m1w * (float)sin(pj1);
    double po = -PI_D + o7*(2.0*PI_D/100.0);
    cd = (float)cos(po);  sd = (float)sin(po);
  }

  // ---- init LDS ----
  if (t < 328) { su[0][t] = 0.f; su[1][t] = 0.f; }
  if (t < 104) d7r[t] = 0.f;
  {
    const float2* x2 = (const float2*)xin + (size_t)b * SSTEPS;
    for (int i = t; i < SSTEPS; i += 1024) avb[i] = x2[i].y;
  }
  if (t < 300) {
    float v = r0[b*300 + t];
    su[0][t] = (t < 200) ? v : fmaxf(v, 0.f);
  }
  __syncthreads();

  float* outb = out + (size_t)b * ((size_t)SSTEPS * 300);
  int p = 0;

  #pragma unroll 1
  for (int s = 0; s < SSTEPS; ++s) {
    const float* suc = su[p];
    float*       sun = su[p^1];

    // ---------- phase 1: r_HD_new (threads 0..799) ----------
    if (p1) {
      f2 vv2[10];
      {
        const float4* vp = (const float4*)(suc + 20*r1);
        float4 V0=vp[0], V1=vp[1], V2=vp[2], V3=vp[3], V4=vp[4];
        vv2[0] = f2{V0.x, V0.y}; vv2[1] = f2{V0.z, V0.w};
        vv2[2] = f2{V1.x, V1.y}; vv2[3] = f2{V1.z, V1.w};
        vv2[4] = f2{V2.x, V2.y}; vv2[5] = f2{V2.z, V2.w};
        vv2[6] = f2{V3.x, V3.y}; vv2[7] = f2{V3.z, V3.w};
        vv2[8] = f2{V4.x, V4.y}; vv2[9] = f2{V4.z, V4.w};
      }
      float hd0 = suc[g], hd1 = suc[g+50];
      f2 a0 = f2{0.f,0.f}, b0 = f2{0.f,0.f};
      f2 a1 = f2{0.f,0.f}, b1 = f2{0.f,0.f};
      #pragma unroll
      for (int q2 = 0; q2 < 10; q2 += 2) {
        a0 = pk_fma(w1p[0][q2],   vv2[q2],   a0);
        b0 = pk_fma(w1p[0][q2+1], vv2[q2+1], b0);
        a1 = pk_fma(w1p[1][q2],   vv2[q2],   a1);
        b1 = pk_fma(w1p[1][q2+1], vv2[q2+1], b1);
      }
      float e0 = (a0[0] + a0[1]) + (b0[0] + b0[1]);
      float e1 = (a1[0] + a1[1]) + (b1[0] + b1[1]);
      if (r1 >= 10) { e0 *= hd0; e1 *= hd1; }   // D7 cols multiply r_HD
      e0 = scan16(e0);
      e1 = scan16(e1);
      if (r1 == 15) {
        float h0 = fmaf(0.001f, fmaf(-10.25f, hd0, e0), hd0);
        float h1 = fmaf(0.001f, fmaf(-10.25f, hd1, e1), hd1);
        sun[g]    = h0;
        sun[g+50] = h1;
      }
    } else if (pd7) {
      // (T0 for this step computed below in phase 2 from suc; v2 computed it
      //  here — keep v2's placement)
    } else if (pst) {
      if (s > 0) {     // stream output row s-1 while others compute
        float* od = outb + (size_t)(s-1) * 300;
        #pragma unroll
        for (int u = 0; u < 5; ++u) {
          int idx = dl + 64*u;
          if (idx < 300) od[idx] = (idx < 200) ? suc[idx] : d7r[idx-200];
        }
      }
    }
    float T0loc = 0.f;
    if (pd7) {
      // T0 = sum relu(D7(s-1)) — step-old data, runs in phase-1 window
      float x = 0.f;
      if (dl < 50) { float2 z = *(const float2*)(suc + 200 + 2*dl); x = z.x + z.y; }
      T0loc = wave_sum(x);
    }
    __syncthreads();

    // ---------- phase 2a: AVp/AVm (threads 0..399), ONE shared dot ----------
    if (pav) {
      const float4* hp = (const float4*)sun;    // hdnew[0..99] + zero pad
      float4 H0 = hp[qa], H1 = hp[qa+8], H2 = hp[qa+16], H3 = hp[qa+24];
      f2 hh2[8];
      hh2[0] = f2{H0.x, H0.y}; hh2[1] = f2{H0.z, H0.w};
      hh2[2] = f2{H1.x, H1.y}; hh2[3] = f2{H1.z, H1.w};
      hh2[4] = f2{H2.x, H2.y}; hh2[5] = f2{H2.z, H2.w};
      hh2[6] = f2{H3.x, H3.y}; hh2[7] = f2{H3.z, H3.w};
      f2 d0 = f2{0.f,0.f}, d1 = f2{0.f,0.f};
      #pragma unroll
      for (int u = 0; u < 8; u += 2) {
        d0 = pk_fma(wavp[u],   hh2[u],   d0);
        d1 = pk_fma(wavp[u+1], hh2[u+1], d1);
      }
      float d = scan8((d0[0] + d0[1]) + (d1[0] + d1[1]));
      if (qa == 7) {
        float av   = avb[s];
        float gp   = av * 1000.0f;       // av/DT, AV_OFFSET=0
        float oldp = suc[100+a], oldm = suc[150+a];
        float np_  = fmaf(0.1f, fmaf(gp,  d, -oldp), oldp);   // DT/TAU_AV = 0.1
        float nm_  = fmaf(0.1f, fmaf(-gp, d, -oldm), oldm);
        sun[100+a] = np_;
        sun[150+a] = nm_;
      }
    }

    // ---------- phase 2b: D7 (waves 13,14; memoryless, rank-3 factorized) ----------
    if (pd7) {
      float2 y2 = *(const float2*)(sun + 2*dl);        // raw hdnew (masked x 0)
      float y0 = fmaxf(y2.x, 0.f), y1 = fmaxf(y2.y, 0.f);
      float pS0 = fmaf(m1w, y1,   m0w * y0);
      float pC  = fmaf(cw1, y1,   cw0 * y0);
      float pS  = fmaf(sw1, y1,   sw0 * y0);
      float S0 = wave_sum(pS0);
      float C  = wave_sum(pC);
      float S  = wave_sum(pS);
      if (o7 < 100) {
        float d7 = fmaf(0.002f, T0loc, 0.01f * (S0 - fmaf(cd, C, sd * S)));
        sun[200+o7] = fmaxf(d7, 0.f);
        d7r[o7]     = d7;
      }
    }
    __syncthreads();
    p ^= 1;
  }

  // ---------- epilogue: output row 4999 + final carry ----------
  if (t < 300) {
    float v = (t < 200) ? su[p][t] : d7r[t-200];
    outb[(size_t)(SSTEPS-1) * 300 + t] = v;
    out[(size_t)64 * SSTEPS * 300 + (size_t)b * 300 + t] = v;
  }
}

extern "C" void kernel_launch(void* const* d_in, const int* in_sizes, int n_in,
                              void* d_out, int out_size, void* d_ws, size_t ws_size,
                              hipStream_t stream) {
  drosoph_rnn_kernel<<<64, 1024, 0, stream>>>(
      (const float*)d_in[0],  // inputs
      (const float*)d_in[1],  // r0
      (const float*)d_in[2],  // W_HD_HD
      (const float*)d_in[3],  // W_HD_AVplus
      (const float*)d_in[4],  // W_HD_AVminus
      (const float*)d_in[5],  // W_AVplus_HD
      (const float*)d_in[6],  // W_AVminus_HD
      (const float*)d_in[7],  // W_Del7_HD
      (const float*)d_in[8],  // W_Del7_Del7
      (const float*)d_in[9],  // W_HD_Del7
      (float*)d_out);
}